// Round 1
// 113.560 us; speedup vs baseline: 1.0147x; 1.0147x over previous
//
#include <hip/hip_runtime.h>

// GauntTensorProductFixedParity — R7: amortize operand fragments over 4 row-tiles/wave.
//
//   A1t = (W1 @ Y^T)^T  [132x64 -> padded 144x64]  (fp16, A-frag-swizzled)
//   A2t = (W2 @ Y^T)^T
//   Ywt = Yw^T          [25x132 -> padded 32x144]  (fp16, A-frag for K=16)
//
//   GEMM1 (16x16x32 f16): G^T = A1t · in^T  -> C-layout: lane holds
//          p = quad*4+i, row = lo16  == B-operand layout of K=16 MFMA.
//   H = G1^T ⊙ G2^T (elementwise in registers, f32->f16)
//   GEMM2 (16x16x16 f16): out^T = Ywt · H    -> C-layout: lane holds
//          s = quad*4+i, row = lo16 -> 16B-contiguous per-lane stores.
//
// R7 change vs R6: each wave owns FOUR 16-row tiles (64 rows) instead of two.
// Per-wave operand-fragment reads (46 KB from L2) are amortized over 2x the
// rows: chip-wide operand traffic 188 MB -> 94 MB. Grid 512 blocks x 256 thr,
// 256 rows/block. VGPR ~160 -> __launch_bounds__(256,3) (12 waves/CU).
// Precompute kernel spread over 64 blocks (was 16) for one-pass execution.

typedef _Float16 f16x8 __attribute__((ext_vector_type(8)));
typedef _Float16 f16x4 __attribute__((ext_vector_type(4)));
typedef float f32x4 __attribute__((ext_vector_type(4)));
typedef float f32x4u __attribute__((ext_vector_type(4), aligned(4)));

namespace {
constexpr int kD = 64, kS = 25, kP = 132;
constexpr int kBlock = 256, kM = 256;            // rows per block (4 waves x 64 rows)
// d_ws layout in _Float16 units:
//   A1t frags [pt(9)][ks(2)][lane(64)][j(8)] = 9216
//   A2t frags                                 = 9216
//   Ywt frags [st(2)][pt(9)][lane(64)][i(4)]  = 4608
constexpr int kWsA2 = 9216, kWsYw = 18432;
}

// ---- Precompute swizzled fp16 operands into d_ws (every launch) ----
__global__ void precompute_kernel(const float* __restrict__ W1,
                                  const float* __restrict__ W2,
                                  const float* __restrict__ Y,
                                  const float* __restrict__ Yw,
                                  _Float16* __restrict__ ws) {
    const int t0 = blockIdx.x * blockDim.x + threadIdx.x;
    const int stride = gridDim.x * blockDim.x;
    // A1t/A2t: value A1t[p][d] = sum_s W[d][s] Y[p][s];  p from lane&15+tile,
    // d from ks*32 + quad*8 + j.  p >= 132 -> 0.
    for (int e = t0; e < 9216; e += stride) {
        const int j = e & 7, lane = (e >> 3) & 63, ks = (e >> 9) & 1, pt = e >> 10;
        const int d = ks * 32 + (lane >> 4) * 8 + j;     // 0..63
        const int p = pt * 16 + (lane & 15);             // 0..143
        float v1 = 0.f, v2 = 0.f;
        if (p < kP) {
            const float* yr = Y + p * kS;
            const float* w1 = W1 + d * kS;
            const float* w2 = W2 + d * kS;
            #pragma unroll
            for (int s = 0; s < kS; ++s) {
                v1 = fmaf(w1[s], yr[s], v1);
                v2 = fmaf(w2[s], yr[s], v2);
            }
        }
        ws[e]         = (_Float16)v1;
        ws[kWsA2 + e] = (_Float16)v2;
    }
    // Ywt: A-frag (K=16) value Ywt[s][p] = Yw[p][s]; s = st*16 + lane&15,
    // p = pt*16 + quad*4 + i.  Zero outside [25) x [132).
    for (int e = t0; e < 4608; e += stride) {
        const int i = e & 3, lane = (e >> 2) & 63, r = e >> 8;  // r 0..17
        const int pt = r % 9, st = r / 9;
        const int p = pt * 16 + ((lane >> 4) & 3) * 4 + i;      // 0..143
        const int s = st * 16 + (lane & 15);                    // 0..31
        ws[kWsYw + e] = (s < kS && p < kP) ? (_Float16)Yw[p * kS + s]
                                           : (_Float16)0.f;
    }
}

__device__ __forceinline__ f16x8 ld8(const _Float16* p) {
    return *reinterpret_cast<const f16x8*>(p);
}
__device__ __forceinline__ f16x4 ld4(const _Float16* p) {
    return *reinterpret_cast<const f16x4*>(p);
}
__device__ __forceinline__ f16x8 cvt8h(f32x4 u, f32x4 v) {
    f16x8 r;
    r[0] = (_Float16)u[0]; r[1] = (_Float16)u[1];
    r[2] = (_Float16)u[2]; r[3] = (_Float16)u[3];
    r[4] = (_Float16)v[0]; r[5] = (_Float16)v[1];
    r[6] = (_Float16)v[2]; r[7] = (_Float16)v[3];
    return r;
}

__global__ __launch_bounds__(kBlock, 3) void gaunt_mfma7(
    const float* __restrict__ in1, const float* __restrict__ in2,
    const _Float16* __restrict__ ws, float* __restrict__ out)
{
    const int tid  = threadIdx.x;
    const int lane = tid & 63;
    const int w    = __builtin_amdgcn_readfirstlane(tid >> 6);
    const int lo16 = lane & 15, quad = lane >> 4;

    // ---- input B-frags (in^T): lane n=row=lo16, k=d=ks*32+quad*8+j ----
    const long long base = (long long)blockIdx.x * (kM * kD);
    f16x8 b1[4][2], b2[4][2];
    #pragma unroll
    for (int rt = 0; rt < 4; ++rt) {
        const int row = (4 * w + rt) * 16 + lo16;
        const float* p1 = in1 + base + row * kD + quad * 8;
        const float* p2 = in2 + base + row * kD + quad * 8;
        #pragma unroll
        for (int ks = 0; ks < 2; ++ks) {
            const f32x4 u1 = *reinterpret_cast<const f32x4*>(p1 + ks * 32);
            const f32x4 v1 = *reinterpret_cast<const f32x4*>(p1 + ks * 32 + 4);
            const f32x4 u2 = *reinterpret_cast<const f32x4*>(p2 + ks * 32);
            const f32x4 v2 = *reinterpret_cast<const f32x4*>(p2 + ks * 32 + 4);
            b1[rt][ks] = cvt8h(u1, v1);
            b2[rt][ks] = cvt8h(u2, v2);
        }
    }

    const _Float16* wsA1 = ws;
    const _Float16* wsA2 = ws + kWsA2;
    const _Float16* wsYw = ws + kWsYw;

    f32x4 oacc[4][2];
    #pragma unroll
    for (int rt = 0; rt < 4; ++rt)
        #pragma unroll
        for (int st = 0; st < 2; ++st)
            oacc[rt][st] = (f32x4){0.f, 0.f, 0.f, 0.f};

    // ---- double-buffered operand frags over 9 p-tiles ----
    f16x8 a1c[2], a2c[2], a1n[2], a2n[2];
    f16x4 ywc[2], ywn[2];
    #pragma unroll
    for (int ks = 0; ks < 2; ++ks) {
        a1c[ks] = ld8(&wsA1[ks * 512 + lane * 8]);
        a2c[ks] = ld8(&wsA2[ks * 512 + lane * 8]);
    }
    #pragma unroll
    for (int st = 0; st < 2; ++st)
        ywc[st] = ld4(&wsYw[(st * 9) * 256 + lane * 4]);

    #pragma unroll 1
    for (int pt = 0; pt < 9; ++pt) {
        if (pt < 8) {
            #pragma unroll
            for (int ks = 0; ks < 2; ++ks) {
                a1n[ks] = ld8(&wsA1[((pt + 1) * 2 + ks) * 512 + lane * 8]);
                a2n[ks] = ld8(&wsA2[((pt + 1) * 2 + ks) * 512 + lane * 8]);
            }
            #pragma unroll
            for (int st = 0; st < 2; ++st)
                ywn[st] = ld4(&wsYw[(st * 9 + pt + 1) * 256 + lane * 4]);
        }
        #pragma unroll
        for (int rt = 0; rt < 4; ++rt) {
            f32x4 g1 = (f32x4){0.f, 0.f, 0.f, 0.f};
            f32x4 g2 = (f32x4){0.f, 0.f, 0.f, 0.f};
            #pragma unroll
            for (int ks = 0; ks < 2; ++ks) {
                g1 = __builtin_amdgcn_mfma_f32_16x16x32_f16(a1c[ks], b1[rt][ks], g1, 0, 0, 0);
                g2 = __builtin_amdgcn_mfma_f32_16x16x32_f16(a2c[ks], b2[rt][ks], g2, 0, 0, 0);
            }
            f16x4 h;
            h[0] = (_Float16)(g1[0] * g2[0]);
            h[1] = (_Float16)(g1[1] * g2[1]);
            h[2] = (_Float16)(g1[2] * g2[2]);
            h[3] = (_Float16)(g1[3] * g2[3]);
            #pragma unroll
            for (int st = 0; st < 2; ++st)
                oacc[rt][st] = __builtin_amdgcn_mfma_f32_16x16x16f16(
                    ywc[st], h, oacc[rt][st], 0, 0, 0);
        }
        #pragma unroll
        for (int ks = 0; ks < 2; ++ks) { a1c[ks] = a1n[ks]; a2c[ks] = a2n[ks]; }
        ywc[0] = ywn[0]; ywc[1] = ywn[1];
    }

    // ---- stores: out^T C-layout -> per-lane 16B-contiguous runs ----
    const long long ob = (long long)blockIdx.x * (kM * kS);
    #pragma unroll
    for (int rt = 0; rt < 4; ++rt) {
        const int row = (4 * w + rt) * 16 + lo16;
        float* rp = out + ob + (long long)row * kS;
        // st=0: s = quad*4 + i, 0..15 all valid
        *reinterpret_cast<f32x4u*>(rp + quad * 4) = oacc[rt][0];
        // st=1: s = 16 + quad*4 + i, valid while < 25
        if (quad < 2) {
            *reinterpret_cast<f32x4u*>(rp + 16 + quad * 4) = oacc[rt][1];
        } else if (quad == 2) {
            rp[24] = oacc[rt][1][0];
        }
    }
}

extern "C" void kernel_launch(void* const* d_in, const int* in_sizes, int n_in,
                              void* d_out, int out_size, void* d_ws, size_t ws_size,
                              hipStream_t stream) {
    const float* in1 = (const float*)d_in[0];   // [N, 64]
    const float* in2 = (const float*)d_in[1];   // [N, 64]
    const float* W1  = (const float*)d_in[2];   // [64, 25]
    const float* W2  = (const float*)d_in[3];   // [64, 25]
    const float* Y   = (const float*)d_in[4];   // [132, 25]
    const float* Yw  = (const float*)d_in[5];   // [132, 25]
    float* out = (float*)d_out;                 // [N, 25]
    _Float16* ws = (_Float16*)d_ws;             // 23040 halfs used

    precompute_kernel<<<64, 256, 0, stream>>>(W1, W2, Y, Yw, ws);

    const int n_rows = in_sizes[0] / kD;        // 131072
    const int grid = n_rows / kM;               // 512
    gaunt_mfma7<<<grid, kBlock, 0, stream>>>(in1, in2, ws, out);
}